// Round 6
// baseline (352.705 us; speedup 1.0000x reference)
//
#include <hip/hip_runtime.h>

// B = in_sizes[0]/840, L=40, A=21. One thread per row. 128-thread blocks =
// 2 waves over the SAME 64 rows, each wave handling 20 of the 40 positions
// (sum-of-cumprod splits: v = S1 + P1*S2, j = J1 + J2). Wave-private LDS
// slices, zero barriers in the main loop (R4's fence discipline + in-order
// DS), single LDS buffer per wave, depth-2 register prefetch. CPOS=1 keeps
// LDS at 10.5 KB/block -> 8 blocks/CU = 16 waves/CU = 4 waves/SIMD (2x R4).
#define LPOS 40
#define AA   21
#define ROWF (LPOS*AA)        // 840 floats per row
#define HPOS (LPOS/2)         // 20 positions per wave
#define NCH  HPOS             // 20 bodies (1 position per body)
#define NTHR 128              // two waves
#define SLICE (64*AA)         // 1344 floats = 5376 B per wave slice

// Compiler-only fence: orders memory ops across the staging transpose
// (single-thread alias analysis would otherwise hoist next body's ds_reads
// above this body's ds_writes — the R2/R3 bug). HW per-wave DS is in-order.
#define FENCE() asm volatile("" ::: "memory")

__global__ __launch_bounds__(NTHR, 4) void cm_kernel(
    const float* __restrict__ x,
    const float* __restrict__ vg,
    const float* __restrict__ jg,
    float* __restrict__ out)
{
    __shared__ float lds[2][SLICE];   // per-wave slices, 10752 B total

    const int tid  = threadIdx.x;
    const int lane = tid & 63;
    const int wv   = tid >> 6;                       // 0: pos 0..19, 1: 20..39
    const long long row0 = (long long)blockIdx.x * 64;

    const float* xb  = x  + row0 * ROWF + wv * HPOS * AA;  // wave's first chunk
    const float* vgw = vg + wv * HPOS * AA;
    const float* jgw = jg + wv * HPOS * AA;

    // Per-lane dword offsets for body 0: flat slot f = lane + 64*i over
    // [64 rows][21 floats]; r = f/21, e = f%21, goff = r*840 + e.
    // Step f += 64  =>  r += 3, e += 1  (wrap: e -= 21, r += 1).
    int goff[AA];
    {
        int r = lane / AA;
        int e = lane - r * AA;
        int off = r * ROWF + e;
        #pragma unroll
        for (int i = 0; i < AA; ++i) {
            goff[i] = off;
            e += 1; off += 3 * ROWF + 1;
            if (e >= AA) { e -= AA; off += ROWF - AA; }
        }
    }

    float rgA[AA], rgB[AA];

    // Prologue: chunk0 -> rgA, chunk1 -> rgB (in flight), rgA -> LDS (vmcnt
    // waits rgA only), rgA <- chunk2.
    // Invariant entering c=0: LDS = chunk0; rgB = chunk1; rgA = chunk2.
    #pragma unroll
    for (int i = 0; i < AA; ++i) rgA[i] = xb[goff[i]];
    #pragma unroll
    for (int i = 0; i < AA; ++i) rgB[i] = xb[goff[i] + AA];
    FENCE();
    #pragma unroll
    for (int i = 0; i < AA; ++i) lds[wv][lane + i * 64] = rgA[i];
    FENCE();
    #pragma unroll
    for (int i = 0; i < AA; ++i) rgA[i] = xb[goff[i] + 2 * AA];
    FENCE();

    float run = 1.0f, vsum = 0.0f, jsum = 0.0f;

    // Body: compute position c from LDS; overwrite LDS with chunk c+1 (WAR
    // safe: in-order DS + fences); refill RGW with chunk c+3 (depth-2).
    #define BODY(c, RGW)                                                   \
      {                                                                    \
        const float* xs = &lds[wv][lane * AA];                             \
        float m = 0.f, jm = 0.f;                                           \
        _Pragma("unroll")                                                  \
        for (int a = 0; a < AA; ++a) {                                     \
          const float xv = xs[a];                                          \
          m  = fmaf(xv, vgw[(c) * AA + a], m);    /* uniform -> s_load */  \
          jm = fmaf(xv, jgw[(c) * AA + a], jm);                            \
        }                                                                  \
        run *= m; vsum += run; jsum += jm;                                 \
        FENCE();                                                           \
        if ((c) + 1 < NCH) {                                               \
          _Pragma("unroll")                                                \
          for (int i = 0; i < AA; ++i) lds[wv][lane + i * 64] = RGW[i];    \
          FENCE();                                                         \
          if ((c) + 3 < NCH) {                                             \
            _Pragma("unroll")                                              \
            for (int i = 0; i < AA; ++i)                                   \
              RGW[i] = xb[goff[i] + ((c) + 3) * AA];                       \
            FENCE();                                                       \
          }                                                                \
        }                                                                  \
      }

    for (int c = 0; c < NCH; c += 2) {
        BODY(c,     rgB)   // compute c;   stage c+1 (rgB); rgB <- c+3
        BODY(c + 1, rgA)   // compute c+1; stage c+2 (rgA); rgA <- c+4
    }

    // Combine: wave1 publishes (S2, J2); wave0 forms v = S1 + P1*S2,
    // j = J1 + J2. Reuses wave1's slice after its last read (in-order DS).
    if (wv == 1) {
        FENCE();
        ((float2*)&lds[1][0])[lane] = make_float2(vsum, jsum);
    }
    __syncthreads();
    if (wv == 0) {
        const float2 s2 = ((float2*)&lds[1][0])[lane];
        ((float2*)out)[row0 + lane] =
            make_float2(fmaf(run, s2.x, vsum), jsum + s2.y);
    }
}

extern "C" void kernel_launch(void* const* d_in, const int* in_sizes, int n_in,
                              void* d_out, int out_size, void* d_ws, size_t ws_size,
                              hipStream_t stream) {
    const float* x  = (const float*)d_in[0];
    const float* vg = (const float*)d_in[1];
    const float* jg = (const float*)d_in[2];
    float* out      = (float*)d_out;

    const int B    = in_sizes[0] / ROWF;   // 131072
    const int grid = B / 64;               // 2048 blocks of 128 threads

    cm_kernel<<<grid, NTHR, 0, stream>>>(x, vg, jg, out);
}

// Round 7
// 119.791 us; speedup vs baseline: 2.9444x; 2.9444x over previous
//
#include <hip/hip_runtime.h>

// B = in_sizes[0]/840, L=40, A=21. One thread per row. 128-thread blocks =
// 2 waves over the SAME 64 rows, each wave handling 20 of the 40 positions
// (sum-of-cumprod splits: v = S1 + P1*S2, j = J1 + J2). Wave-private LDS
// slices, zero barriers in the main loop, single LDS buffer per wave,
// depth-2 register prefetch. 10.5 KB LDS/block; grid B/64 = 2048 -> 8
// blocks/CU = 16 waves/CU = 4 waves/SIMD.
// __launch_bounds__(128, 2): R5's (128,4) empirically capped VGPR at 64
// (hipcc treated arg2 as workgroups/EU: 4wg x 2waves = 8 waves -> 512/8=64)
// and spilled ~63 live regs to scratch (WRITE_SIZE 353 MB). (128,2) caps at
// >=128 under either interpretation; live regs ~90 -> no spill.
#define LPOS 40
#define AA   21
#define ROWF (LPOS*AA)        // 840 floats per row
#define HPOS (LPOS/2)         // 20 positions per wave
#define NCH  HPOS             // 20 bodies (1 position per body)
#define NTHR 128              // two waves
#define SLICE (64*AA)         // 1344 floats = 5376 B per wave slice

// Compiler-only fence: orders memory ops across the staging transpose
// (single-thread alias analysis would otherwise hoist next body's ds_reads
// above this body's ds_writes — the R2/R3 bug). HW per-wave DS is in-order.
#define FENCE() asm volatile("" ::: "memory")

__global__ __launch_bounds__(NTHR, 2) void cm_kernel(
    const float* __restrict__ x,
    const float* __restrict__ vg,
    const float* __restrict__ jg,
    float* __restrict__ out)
{
    __shared__ float lds[2][SLICE];   // per-wave slices, 10752 B total

    const int tid  = threadIdx.x;
    const int lane = tid & 63;
    const int wv   = tid >> 6;                       // 0: pos 0..19, 1: 20..39
    const long long row0 = (long long)blockIdx.x * 64;

    const float* xb  = x  + row0 * ROWF + wv * HPOS * AA;  // wave's first chunk
    const float* vgw = vg + wv * HPOS * AA;
    const float* jgw = jg + wv * HPOS * AA;

    // Per-lane dword offsets for body 0: flat slot f = lane + 64*i over
    // [64 rows][21 floats]; r = f/21, e = f%21, goff = r*840 + e.
    // Step f += 64  =>  r += 3, e += 1  (wrap: e -= 21, r += 1).
    int goff[AA];
    {
        int r = lane / AA;
        int e = lane - r * AA;
        int off = r * ROWF + e;
        #pragma unroll
        for (int i = 0; i < AA; ++i) {
            goff[i] = off;
            e += 1; off += 3 * ROWF + 1;
            if (e >= AA) { e -= AA; off += ROWF - AA; }
        }
    }

    float rgA[AA], rgB[AA];

    // Prologue: chunk0 -> rgA, chunk1 -> rgB (in flight), rgA -> LDS (vmcnt
    // waits rgA only), rgA <- chunk2.
    // Invariant entering c=0: LDS = chunk0; rgB = chunk1; rgA = chunk2.
    #pragma unroll
    for (int i = 0; i < AA; ++i) rgA[i] = xb[goff[i]];
    #pragma unroll
    for (int i = 0; i < AA; ++i) rgB[i] = xb[goff[i] + AA];
    FENCE();
    #pragma unroll
    for (int i = 0; i < AA; ++i) lds[wv][lane + i * 64] = rgA[i];
    FENCE();
    #pragma unroll
    for (int i = 0; i < AA; ++i) rgA[i] = xb[goff[i] + 2 * AA];
    FENCE();

    float run = 1.0f, vsum = 0.0f, jsum = 0.0f;

    // Body: compute position c from LDS; overwrite LDS with chunk c+1 (WAR
    // safe: in-order DS + fences); refill RGW with chunk c+3 (depth-2).
    #define BODY(c, RGW)                                                   \
      {                                                                    \
        const float* xs = &lds[wv][lane * AA];                             \
        float m = 0.f, jm = 0.f;                                           \
        _Pragma("unroll")                                                  \
        for (int a = 0; a < AA; ++a) {                                     \
          const float xv = xs[a];                                          \
          m  = fmaf(xv, vgw[(c) * AA + a], m);    /* uniform -> s_load */  \
          jm = fmaf(xv, jgw[(c) * AA + a], jm);                            \
        }                                                                  \
        run *= m; vsum += run; jsum += jm;                                 \
        FENCE();                                                           \
        if ((c) + 1 < NCH) {                                               \
          _Pragma("unroll")                                                \
          for (int i = 0; i < AA; ++i) lds[wv][lane + i * 64] = RGW[i];    \
          FENCE();                                                         \
          if ((c) + 3 < NCH) {                                             \
            _Pragma("unroll")                                              \
            for (int i = 0; i < AA; ++i)                                   \
              RGW[i] = xb[goff[i] + ((c) + 3) * AA];                       \
            FENCE();                                                       \
          }                                                                \
        }                                                                  \
      }

    for (int c = 0; c < NCH; c += 2) {
        BODY(c,     rgB)   // compute c;   stage c+1 (rgB); rgB <- c+3
        BODY(c + 1, rgA)   // compute c+1; stage c+2 (rgA); rgA <- c+4
    }

    // Combine: wave1 publishes (S2, J2); wave0 forms v = S1 + P1*S2,
    // j = J1 + J2. Reuses wave1's slice after its last read (in-order DS).
    if (wv == 1) {
        FENCE();
        ((float2*)&lds[1][0])[lane] = make_float2(vsum, jsum);
    }
    __syncthreads();
    if (wv == 0) {
        const float2 s2 = ((float2*)&lds[1][0])[lane];
        ((float2*)out)[row0 + lane] =
            make_float2(fmaf(run, s2.x, vsum), jsum + s2.y);
    }
}

extern "C" void kernel_launch(void* const* d_in, const int* in_sizes, int n_in,
                              void* d_out, int out_size, void* d_ws, size_t ws_size,
                              hipStream_t stream) {
    const float* x  = (const float*)d_in[0];
    const float* vg = (const float*)d_in[1];
    const float* jg = (const float*)d_in[2];
    float* out      = (float*)d_out;

    const int B    = in_sizes[0] / ROWF;   // 131072
    const int grid = B / 64;               // 2048 blocks of 128 threads

    cm_kernel<<<grid, NTHR, 0, stream>>>(x, vg, jg, out);
}